// Round 13
// baseline (167.504 us; speedup 1.0000x reference)
//
#include <hip/hip_runtime.h>
#include <hip/hip_bf16.h>
#include <math.h>

#define T_SEQ 2048
#define DM 1024
#define NH 16
#define DH 64
#define CHUNK 64
#define NCHUNK (T_SEQ / CHUNK)   // 32

typedef __hip_bfloat16 bf16;
typedef __attribute__((ext_vector_type(8))) short short8;
typedef __attribute__((ext_vector_type(4))) short short4v;
typedef __attribute__((ext_vector_type(4))) float f32x4;

static __device__ __forceinline__ short f2b_bits(float f) {
  bf16 t = __float2bfloat16(f);
  short s;
  __builtin_memcpy(&s, &t, 2);
  return s;
}
static __device__ __forceinline__ float b2f(short s) {
  unsigned int u = ((unsigned int)(unsigned short)s) << 16;
  float f;
  __builtin_memcpy(&f, &u, 4);
  return f;
}
// gated ELU+1: elu(x)+1 = x>0 ? x+1 : exp(x)
static __device__ __forceinline__ float gelu1(float raw, float gate, float inv) {
  float x = raw * gate * inv;
  return x > 0.f ? x + 1.f : __expf(x);
}
static __device__ __forceinline__ void gload16(const void* g, void* l) {
  __builtin_amdgcn_global_load_lds((const __attribute__((address_space(1))) void*)g,
                                   (__attribute__((address_space(3))) void*)l, 16, 0, 0);
}

// ---------------------------------------------------------------------------
// prep: blocks 0..2047 = LayerNorm rows (blocks 0..7 also zero gate_accum);
//       blocks 2048..  = fp32->bf16 weight conversion (qkv|gate|proj).
// ---------------------------------------------------------------------------
#define PREP_WBLOCKS (5 * DM * DM / 4 / 256)   // 5120
__global__ __launch_bounds__(256) void prep_kernel(
    const float* __restrict__ x, const float* __restrict__ g,
    const float* __restrict__ b, const float* __restrict__ qkv_w,
    const float* __restrict__ gate_w, const float* __restrict__ proj_w,
    bf16* __restrict__ xn, bf16* __restrict__ xbf,
    bf16* __restrict__ wqkv, bf16* __restrict__ wgate, bf16* __restrict__ wproj,
    float* __restrict__ gate_accum) {
  const int blk = blockIdx.x;
  if (blk < T_SEQ) {
    const int row = blk;
    if (row < 8) gate_accum[row * 256 + threadIdx.x] = 0.f;
    const float* xr = x + (size_t)row * DM;
    float vals[4];
    float s = 0.f, s2 = 0.f;
#pragma unroll
    for (int i = 0; i < 4; i++) {
      float v = xr[threadIdx.x + i * 256];
      vals[i] = v;
      s += v;
      s2 += v * v;
    }
#pragma unroll
    for (int m = 1; m < 64; m <<= 1) {
      s += __shfl_xor(s, m, 64);
      s2 += __shfl_xor(s2, m, 64);
    }
    __shared__ float red[8];
    const int wid = threadIdx.x >> 6;
    if ((threadIdx.x & 63) == 0) {
      red[wid] = s;
      red[4 + wid] = s2;
    }
    __syncthreads();
    s = red[0] + red[1] + red[2] + red[3];
    s2 = red[4] + red[5] + red[6] + red[7];
    const float mean = s * (1.f / DM);
    const float var = s2 * (1.f / DM) - mean * mean;
    const float rstd = rsqrtf(var + 1e-5f);
#pragma unroll
    for (int i = 0; i < 4; i++) {
      int idx = threadIdx.x + i * 256;
      float v = (vals[i] - mean) * rstd * g[idx] + b[idx];
      xn[(size_t)row * DM + idx] = __float2bfloat16(v);
      xbf[(size_t)row * DM + idx] = __float2bfloat16(vals[i]);
    }
  } else {
    constexpr int NQ = 3 * DM * DM / 4, NS = DM * DM / 4;
    int i = (blk - T_SEQ) * 256 + threadIdx.x;
    const float* src;
    bf16* dst;
    int j;
    if (i < NQ) { src = qkv_w; dst = wqkv; j = i; }
    else if (i < NQ + NS) { src = gate_w; dst = wgate; j = i - NQ; }
    else { src = proj_w; dst = wproj; j = i - NQ - NS; }
    float4 v = ((const float4*)src)[j];
    short4v sv;
    sv.x = f2b_bits(v.x); sv.y = f2b_bits(v.y); sv.z = f2b_bits(v.z); sv.w = f2b_bits(v.w);
    *(short4v*)&dst[j * 4] = sv;
  }
}

// ---------------------------------------------------------------------------
// Fused gate+qkv GEMM, tile 64x128, BK=64, DOUBLE-BUFFERED single-barrier
// K-loop: stage(it+1) issued before compute(it); loads drain at the NEXT
// barrier having had a compute phase in flight (R12's 2-barrier loop exposed
// full load latency every iter -> 390 TF plateau). LDS 48 KB -> 3 blocks/CU,
// grid (32 n-fast, 32 m) = 1024 blocks.
// ---------------------------------------------------------------------------
__global__ __launch_bounds__(256) void gemm_gateqkv(
    const bf16* __restrict__ xbf, const bf16* __restrict__ xn,
    const bf16* __restrict__ wg, const bf16* __restrict__ wq,
    const float* __restrict__ gate_b, const float* __restrict__ qkv_b,
    short* __restrict__ Gb, float* __restrict__ gate_accum,
    short* __restrict__ Qb, short* __restrict__ Kb, short* __restrict__ Vb,
    short* __restrict__ VbT) {
  constexpr int K = 1024;
  __shared__ __align__(16) short As[2 * 4096];   // 2 bufs x (2 sec x 64 x 32) = 16 KB
  __shared__ __align__(16) short Bs[2 * 8192];   // 2 bufs x (2 sec x 128 x 32) = 32 KB

  const int tid = threadIdx.x;
  const int wid = tid >> 6, lane = tid & 63;
  const int wm = wid >> 1, wn = wid & 1;   // wave tile 32(m) x 64(n)
  const int lm = lane & 15, quad = lane >> 4;

  const int nt = blockIdx.x;
  const bool isGate = nt < 8;
  const int m0 = blockIdx.y * 64;
  const int n0 = (isGate ? nt : nt - 8) * 128;
  const short* Ag = (const short*)(isGate ? xbf : xn);
  const short* Wg = (const short*)(isGate ? wg : wq);

  auto stage = [&](int kb, int p) {
#pragma unroll
    for (int sec = 0; sec < 2; sec++) {
      {  // A: 64 rows x 32 shorts per section
        const int row = tid >> 2, seg = (tid & 3) * 8;
        gload16(&Ag[(size_t)(m0 + row) * K + kb + sec * 32 + seg],
                &As[p * 4096 + sec * 2048 + wid * 512]);
      }
#pragma unroll
      for (int it2 = 0; it2 < 2; it2++) {
        const int idx = it2 * 256 + tid;
        const int row = idx >> 2, seg = (idx & 3) * 8;
        gload16(&Wg[(size_t)(n0 + row) * K + kb + sec * 32 + seg],
                &Bs[p * 8192 + sec * 4096 + (it2 * 256 + wid * 64) * 8]);
      }
    }
  };

  f32x4 zero = {0.f, 0.f, 0.f, 0.f};
  f32x4 acc[2][4];
#pragma unroll
  for (int i = 0; i < 2; i++)
#pragma unroll
    for (int j = 0; j < 4; j++) acc[i][j] = zero;

  stage(0, 0);
  for (int it = 0; it < 16; it++) {
    const int p = it & 1;
    __syncthreads();   // drains buf p loads (in flight during prev compute)
    if (it < 15) stage((it + 1) * 64, p ^ 1);
#pragma unroll
    for (int sec = 0; sec < 2; sec++) {
      short8 afr[2], bfr[4];
#pragma unroll
      for (int i = 0; i < 2; i++)
        afr[i] = *(const short8*)&As[p * 4096 + sec * 2048 + (wm * 32 + i * 16 + lm) * 32 + quad * 8];
#pragma unroll
      for (int j = 0; j < 4; j++)
        bfr[j] = *(const short8*)&Bs[p * 8192 + sec * 4096 + (wn * 64 + j * 16 + lm) * 32 + quad * 8];
#pragma unroll
      for (int i = 0; i < 2; i++)
#pragma unroll
        for (int j = 0; j < 4; j++)
          acc[i][j] = __builtin_amdgcn_mfma_f32_16x16x32_bf16(afr[i], bfr[j], acc[i][j], 0, 0, 0);
    }
  }

  // epilogue: C/D layout col = lane&15, row = quad*4 + r
  if (isGate) {
    float* red = (float*)As;   // 64 rows x 32 slots = 8 KB
    __syncthreads();           // MFMA LDS reads done -> safe to reuse As
#pragma unroll
    for (int i = 0; i < 2; i++) {
#pragma unroll
      for (int r = 0; r < 4; r++) {
        const int rowl = wm * 32 + i * 16 + quad * 4 + r;
        const int row = m0 + rowl;
        float rp = 0.f;
#pragma unroll
        for (int j = 0; j < 4; j++) {
          const int col = n0 + wn * 64 + j * 16 + lm;
          float v = acc[i][j][r] + gate_b[col];
          float sig = 1.f / (1.f + __expf(-v));
          Gb[(size_t)row * DM + col] = f2b_bits(sig);
          rp += sig;
        }
        red[rowl * 32 + wn * 16 + lm] = rp;
      }
    }
    __syncthreads();
    if (tid < 64) {
      float s = 0.f;
#pragma unroll
      for (int t2 = 0; t2 < 32; t2++) s += red[tid * 32 + t2];
      atomicAdd(&gate_accum[m0 + tid], s);
    }
  } else {
#pragma unroll
    for (int i = 0; i < 2; i++) {
      const int rbase = m0 + wm * 32 + i * 16 + quad * 4;
#pragma unroll
      for (int j = 0; j < 4; j++) {
        const int col = n0 + wn * 64 + j * 16 + lm;
        const float bval = qkv_b[col];
#pragma unroll
        for (int r = 0; r < 4; r++) {
          const int row = rbase + r;
          const short bv = f2b_bits(acc[i][j][r] + bval);
          if (col < DM) {
            const int d = col;
            Qb[((size_t)(d >> 6) * T_SEQ + row) * DH + (d & 63)] = bv;
          } else if (col < 2 * DM) {
            const int d = col - DM;
            Kb[((size_t)(d >> 6) * T_SEQ + row) * DH + (d & 63)] = bv;
          } else {
            const int d = col - 2 * DM;
            Vb[((size_t)(d >> 6) * T_SEQ + row) * DH + (d & 63)] = bv;
            VbT[((size_t)(d >> 6) * DH + (d & 63)) * T_SEQ + row] = bv;
          }
        }
      }
    }
  }
}

// ---------------------------------------------------------------------------
// Pass A: per (h,c) RAW chunk sums, stored TRANSPOSED: SkvT[m][d]. Sk_c = col
// sums of gated K. Gating during staging.
// ---------------------------------------------------------------------------
__global__ __launch_bounds__(256, 2) void chunk_sum_mm(const short* __restrict__ Kb,
                                                       const short* __restrict__ Gb,
                                                       const float* __restrict__ ga,
                                                       const short* __restrict__ Vb,
                                                       float* __restrict__ SkvT,
                                                       float* __restrict__ Sk) {
  constexpr int STR = 68;
  __shared__ __align__(16) float Ks2[64 * STR];
  __shared__ __align__(16) float Vs2[64 * STR];
  const int b = blockIdx.x;
  const int h = b >> 5, c = b & 31;
  const int tid = threadIdx.x;
  const int ty = tid >> 4, tx = tid & 15;
  const int d0 = ty * 4, m0 = tx * 4;
  const int t0 = c * CHUNK;
  const size_t cb = ((size_t)h * T_SEQ + t0) * DH;
#pragma unroll
  for (int p = 0; p < 4; p++) {
    int f = p * 256 + tid, row = f >> 4, seg = (f & 15) * 4;
    const int t = t0 + row;
    short4v kr = *(const short4v*)&Kb[cb + row * 64 + seg];
    short4v gr = *(const short4v*)&Gb[(size_t)t * DM + h * 64 + seg];
    short4v vr = *(const short4v*)&Vb[cb + row * 64 + seg];
    const float inv = 1.f / (ga[t] * (1.f / DM) + 1e-5f);
    f32x4 kgv, vv;
#pragma unroll
    for (int e = 0; e < 4; e++) {
      kgv[e] = gelu1(b2f(kr[e]), b2f(gr[e]), inv);
      vv[e] = b2f(vr[e]);
    }
    *(f32x4*)&Ks2[row * STR + seg] = kgv;
    *(f32x4*)&Vs2[row * STR + seg] = vv;
  }
  __syncthreads();
  float acc[4][4] = {};
#pragma unroll 4
  for (int s = 0; s < 64; s++) {
    f32x4 kf = *(const f32x4*)&Ks2[s * STR + d0];
    f32x4 vf = *(const f32x4*)&Vs2[s * STR + m0];
#pragma unroll
    for (int i = 0; i < 4; i++)
#pragma unroll
      for (int j = 0; j < 4; j++) acc[i][j] += kf[i] * vf[j];
  }
  float* outp = SkvT + (size_t)b * 4096;
  // transposed store: SkvT[m][d] = acc[d][m]
#pragma unroll
  for (int i = 0; i < 4; i++)
#pragma unroll
    for (int j = 0; j < 4; j++)
      outp[(m0 + j) * 64 + (d0 + i)] = acc[i][j];
  if (tid < 64) {
    float ss = 0.f;
#pragma unroll 4
    for (int s = 0; s < 64; s++) ss += Ks2[s * STR + tid];
    Sk[b * 64 + tid] = ss;
  }
}

// ---------------------------------------------------------------------------
// Pass B: exclusive prefix over chunks (elementwise, layout-agnostic).
// ---------------------------------------------------------------------------
__global__ __launch_bounds__(256) void scan_excl(float* __restrict__ Skv,
                                                 float* __restrict__ Sk) {
  const int bid = blockIdx.x, tid = threadIdx.x;
  if (bid < 256) {
    const int id = bid * 256 + tid;
    const int h = id >> 12, e = id & 4095;
    float* base = Skv + (size_t)h * NCHUNK * 4096 + e;
    float v[NCHUNK];
#pragma unroll
    for (int c = 0; c < NCHUNK; c++) v[c] = base[(size_t)c * 4096];
    float run = 0.f;
#pragma unroll
    for (int c = 0; c < NCHUNK; c++) {
      float t = v[c];
      base[(size_t)c * 4096] = run;
      run += t;
    }
  } else {
    const int id = (bid - 256) * 256 + tid;
    const int h = id >> 6, e = id & 63;
    float* base = Sk + (size_t)h * NCHUNK * 64 + e;
    float v[NCHUNK];
#pragma unroll
    for (int c = 0; c < NCHUNK; c++) v[c] = base[c * 64];
    float run = 0.f;
#pragma unroll
    for (int c = 0; c < NCHUNK; c++) {
      float t = v[c];
      base[c * 64] = run;
      run += t;
    }
  }
}

// ---------------------------------------------------------------------------
// Pass C (MFMA): per (h,c), 4 waves.
//   S = Qg.Kg^T; O^T = P^T.Qg^T + V^T.S^T; den from masked-S rowsum + q.skp.
// ---------------------------------------------------------------------------
__global__ __launch_bounds__(256, 2) void attn_mfma(const short* __restrict__ Qb,
                                                    const short* __restrict__ Kb,
                                                    const short* __restrict__ Gb,
                                                    const float* __restrict__ ga,
                                                    const short* __restrict__ VbT,
                                                    const float* __restrict__ SkvT,
                                                    const float* __restrict__ Sk,
                                                    bf16* __restrict__ O) {
  constexpr int STR = 72;
  __shared__ __align__(16) short Qs[64 * STR];
  __shared__ __align__(16) short Ks[64 * STR];
  __shared__ __align__(16) short Vt[64 * STR];
  __shared__ __align__(16) short Pt[64 * STR];
  __shared__ __align__(16) short SL[64 * STR];
  __shared__ float denp[64], invden[64], skp[64];
  const int b = blockIdx.x;
  const int h = b >> 5, c = b & 31;
  const int tid = threadIdx.x;
  const int wid = tid >> 6, lane = tid & 63;
  const int lm = lane & 15, quad = lane >> 4;
  const int t0 = c * CHUNK;
  const size_t cb = ((size_t)h * T_SEQ + t0) * DH;
  const float* Pg = SkvT + (size_t)b * 4096;

#pragma unroll
  for (int p = 0; p < 4; p++) {
    const int f = p * 256 + tid, row = f >> 4, seg = (f & 15) * 4;
    const int t = t0 + row;
    short4v qr = *(const short4v*)&Qb[cb + row * 64 + seg];
    short4v kr = *(const short4v*)&Kb[cb + row * 64 + seg];
    short4v gr = *(const short4v*)&Gb[(size_t)t * DM + h * 64 + seg];
    short4v vtr = *(const short4v*)&VbT[((size_t)h * DH + row) * T_SEQ + t0 + seg];
    f32x4 pr = *(const f32x4*)&Pg[row * 64 + seg];
    const float inv = 1.f / (ga[t] * (1.f / DM) + 1e-5f);
    short4v qs, ks, ps;
#pragma unroll
    for (int e = 0; e < 4; e++) {
      qs[e] = f2b_bits(gelu1(b2f(qr[e]), b2f(gr[e]), inv));
      ks[e] = f2b_bits(gelu1(b2f(kr[e]), b2f(gr[e]), inv));
      ps[e] = f2b_bits(pr[e]);
    }
    *(short4v*)&Qs[row * STR + seg] = qs;
    *(short4v*)&Ks[row * STR + seg] = ks;
    *(short4v*)&Vt[row * STR + seg] = vtr;
    *(short4v*)&Pt[row * STR + seg] = ps;
  }
  if (tid < 64) skp[tid] = Sk[b * 64 + tid];
  __syncthreads();  // B1

  f32x4 zero = {0.f, 0.f, 0.f, 0.f};
  // ---- S = Qg.Kg^T ----
  short8 aq[2];
#pragma unroll
  for (int ks = 0; ks < 2; ks++)
    aq[ks] = *(const short8*)&Qs[(wid * 16 + lm) * STR + ks * 32 + quad * 8];
  f32x4 accs[4];
#pragma unroll
  for (int j = 0; j < 4; j++) accs[j] = zero;
#pragma unroll
  for (int j = 0; j < 4; j++)
#pragma unroll
    for (int ks = 0; ks < 2; ks++) {
      short8 bk = *(const short8*)&Ks[(j * 16 + lm) * STR + ks * 32 + quad * 8];
      accs[j] = __builtin_amdgcn_mfma_f32_16x16x32_bf16(aq[ks], bk, accs[j], 0, 0, 0);
    }
  float rowpart[4] = {0.f, 0.f, 0.f, 0.f};
#pragma unroll
  for (int j = 0; j < 4; j++) {
    const int s = j * 16 + lm;
#pragma unroll
    for (int r = 0; r < 4; r++) {
      const int t = wid * 16 + quad * 4 + r;
      float v = (s <= t) ? accs[j][r] : 0.f;
      accs[j][r] = v;
      rowpart[r] += v;
    }
  }
#pragma unroll
  for (int msk = 1; msk < 16; msk <<= 1)
#pragma unroll
    for (int r = 0; r < 4; r++) rowpart[r] += __shfl_xor(rowpart[r], msk, 64);
  if (lm == 0)
#pragma unroll
    for (int r = 0; r < 4; r++) denp[wid * 16 + quad * 4 + r] = rowpart[r];
#pragma unroll
  for (int j = 0; j < 4; j++)
#pragma unroll
    for (int r = 0; r < 4; r++)
      SL[(wid * 16 + quad * 4 + r) * STR + j * 16 + lm] = f2b_bits(accs[j][r]);

  // ---- O1^T = P^T.Qg^T ----
  f32x4 acco[4];
#pragma unroll
  for (int j = 0; j < 4; j++) acco[j] = zero;
  short8 ap[2];
#pragma unroll
  for (int ks = 0; ks < 2; ks++)
    ap[ks] = *(const short8*)&Pt[(wid * 16 + lm) * STR + ks * 32 + quad * 8];
#pragma unroll
  for (int j = 0; j < 4; j++)
#pragma unroll
    for (int ks = 0; ks < 2; ks++) {
      short8 bq = *(const short8*)&Qs[(j * 16 + lm) * STR + ks * 32 + quad * 8];
      acco[j] = __builtin_amdgcn_mfma_f32_16x16x32_bf16(ap[ks], bq, acco[j], 0, 0, 0);
    }
  __syncthreads();  // B2: SL + denp complete

  if (tid < 64) {
    float s = 1e-5f + denp[tid];
    for (int d = 0; d < 64; d++) s += b2f(Qs[tid * STR + d]) * skp[d];
    invden[tid] = 1.f / s;
  }

  // ---- O2^T += V^T.S^T ----
  short8 av[2];
#pragma unroll
  for (int ks = 0; ks < 2; ks++)
    av[ks] = *(const short8*)&Vt[(wid * 16 + lm) * STR + ks * 32 + quad * 8];
#pragma unroll
  for (int j = 0; j < 4; j++)
#pragma unroll
    for (int ks = 0; ks < 2; ks++) {
      short8 bs = *(const short8*)&SL[(j * 16 + lm) * STR + ks * 32 + quad * 8];
      acco[j] = __builtin_amdgcn_mfma_f32_16x16x32_bf16(av[ks], bs, acco[j], 0, 0, 0);
    }
  __syncthreads();  // B3: invden ready

#pragma unroll
  for (int j = 0; j < 4; j++) {
    const int t = j * 16 + lm;
    const float idv = invden[t];
    short4v ov;
#pragma unroll
    for (int r = 0; r < 4; r++) ov[r] = f2b_bits(acco[j][r] * idv);
    *(short4v*)&((short*)O)[(size_t)(t0 + t) * DM + h * 64 + wid * 16 + quad * 4] = ov;
  }
}

// ---------------------------------------------------------------------------
// Proj GEMM: tile 64x64, BK=64, DOUBLE-BUFFERED single-barrier K-loop.
// grid (16 n-fast, 32 m) = 512 blocks. LDS 32 KB.
// ---------------------------------------------------------------------------
__global__ __launch_bounds__(256) void gemm_proj(const bf16* __restrict__ A,
                                                 const bf16* __restrict__ W,
                                                 const float* __restrict__ bias,
                                                 float* __restrict__ Cout) {
  constexpr int K = 1024;
  __shared__ __align__(16) short As[2 * 4096];
  __shared__ __align__(16) short Bs[2 * 4096];

  const int tid = threadIdx.x;
  const int wid = tid >> 6, lane = tid & 63;
  const int wm = wid >> 1, wn = wid & 1;   // wave tile 32x32
  const int lm = lane & 15, quad = lane >> 4;

  const int n0 = blockIdx.x * 64;
  const int m0 = blockIdx.y * 64;
  const short* Ag = (const short*)A;
  const short* Wg = (const short*)W;

  auto stage = [&](int kb, int p) {
#pragma unroll
    for (int sec = 0; sec < 2; sec++) {
      const int row = tid >> 2, seg = (tid & 3) * 8;
      gload16(&Ag[(size_t)(m0 + row) * K + kb + sec * 32 + seg],
              &As[p * 4096 + sec * 2048 + wid * 512]);
      gload16(&Wg[(size_t)(n0 + row) * K + kb + sec * 32 + seg],
              &Bs[p * 4096 + sec * 2048 + wid * 512]);
    }
  };

  f32x4 zero = {0.f, 0.f, 0.f, 0.f};
  f32x4 acc[2][2];
#pragma unroll
  for (int i = 0; i < 2; i++)
#pragma unroll
    for (int j = 0; j < 2; j++) acc[i][j] = zero;

  stage(0, 0);
  for (int it = 0; it < 16; it++) {
    const int p = it & 1;
    __syncthreads();
    if (it < 15) stage((it + 1) * 64, p ^ 1);
#pragma unroll
    for (int sec = 0; sec < 2; sec++) {
      short8 afr[2], bfr[2];
#pragma unroll
      for (int i = 0; i < 2; i++)
        afr[i] = *(const short8*)&As[p * 4096 + sec * 2048 + (wm * 32 + i * 16 + lm) * 32 + quad * 8];
#pragma unroll
      for (int j = 0; j < 2; j++)
        bfr[j] = *(const short8*)&Bs[p * 4096 + sec * 2048 + (wn * 32 + j * 16 + lm) * 32 + quad * 8];
#pragma unroll
      for (int i = 0; i < 2; i++)
#pragma unroll
        for (int j = 0; j < 2; j++)
          acc[i][j] = __builtin_amdgcn_mfma_f32_16x16x32_bf16(afr[i], bfr[j], acc[i][j], 0, 0, 0);
    }
  }
#pragma unroll
  for (int i = 0; i < 2; i++) {
    const int rbase = m0 + wm * 32 + i * 16 + quad * 4;
#pragma unroll
    for (int j = 0; j < 2; j++) {
      const int col = n0 + wn * 32 + j * 16 + lm;
      const float bval = bias[col];
#pragma unroll
      for (int r = 0; r < 4; r++)
        Cout[(size_t)(rbase + r) * DM + col] = acc[i][j][r] + bval;
    }
  }
}

// ---------------------------------------------------------------------------
extern "C" void kernel_launch(void* const* d_in, const int* in_sizes, int n_in,
                              void* d_out, int out_size, void* d_ws, size_t ws_size,
                              hipStream_t stream) {
  (void)in_sizes; (void)n_in; (void)out_size; (void)ws_size;
  const float* x      = (const float*)d_in[0];
  const float* ln_g   = (const float*)d_in[1];
  const float* ln_b   = (const float*)d_in[2];
  const float* qkv_w  = (const float*)d_in[3];
  const float* qkv_b  = (const float*)d_in[4];
  const float* gate_w = (const float*)d_in[5];
  const float* gate_b = (const float*)d_in[6];
  const float* proj_w = (const float*)d_in[7];
  const float* proj_b = (const float*)d_in[8];
  float* out = (float*)d_out;

  char* ws = (char*)d_ws;
  size_t off = 0;
  auto alloc = [&](size_t bytes) {
    void* p = ws + off;
    off += (bytes + 255) & ~(size_t)255;
    return p;
  };
  bf16*  xn       = (bf16*)alloc((size_t)T_SEQ * DM * 2);
  bf16*  xbf      = (bf16*)alloc((size_t)T_SEQ * DM * 2);
  bf16*  wqkv     = (bf16*)alloc((size_t)3 * DM * DM * 2);
  bf16*  wgate    = (bf16*)alloc((size_t)DM * DM * 2);
  bf16*  wproj    = (bf16*)alloc((size_t)DM * DM * 2);
  short* Gb       = (short*)alloc((size_t)T_SEQ * DM * 2);
  float* gate_accum = (float*)alloc((size_t)T_SEQ * 4);
  short* Qb       = (short*)alloc((size_t)T_SEQ * DM * 2);
  short* Kb       = (short*)alloc((size_t)T_SEQ * DM * 2);
  short* Vb       = (short*)alloc((size_t)T_SEQ * DM * 2);
  short* VbT      = (short*)alloc((size_t)T_SEQ * DM * 2);
  bf16*  Obuf     = (bf16*)alloc((size_t)T_SEQ * DM * 2);
  float* SkvT     = (float*)alloc((size_t)NH * NCHUNK * 4096 * 4);
  float* Sk       = (float*)alloc((size_t)NH * NCHUNK * 64 * 4);

  prep_kernel<<<T_SEQ + PREP_WBLOCKS, 256, 0, stream>>>(
      x, ln_g, ln_b, qkv_w, gate_w, proj_w, xn, xbf, wqkv, wgate, wproj, gate_accum);
  gemm_gateqkv<<<dim3(32, 32), 256, 0, stream>>>(xbf, xn, wgate, wqkv, gate_b, qkv_b,
                                                 Gb, gate_accum, Qb, Kb, Vb, VbT);
  chunk_sum_mm<<<NH * NCHUNK, 256, 0, stream>>>(Kb, Gb, gate_accum, Vb, SkvT, Sk);
  scan_excl<<<260, 256, 0, stream>>>(SkvT, Sk);
  attn_mfma<<<NH * NCHUNK, 256, 0, stream>>>(Qb, Kb, Gb, gate_accum, VbT, SkvT, Sk, Obuf);
  gemm_proj<<<dim3(16, 32), 256, 0, stream>>>(Obuf, wproj, proj_b, out);
}